// Round 4
// baseline (255.485 us; speedup 1.0000x reference)
//
#include <hip/hip_runtime.h>
#include <math.h>

// Problem constants (from reference setup_inputs)
#define T_TOKENS 16384
#define DIM      2048
#define NEXP     64
#define TOPK     2

// Flat fp32 output layout: combine | topk_idx | gates | expert_activation
#define OFF_COMBINE 0
#define OFF_IDX     (T_TOKENS * NEXP)
#define OFF_GATES   (OFF_IDX + T_TOKENS * TOPK)
#define OFF_ACT     (OFF_GATES + T_TOKENS * TOPK)

#define WT_PLANE (NEXP * DIM)   // one bf16 plane of transposed w, in elements

#define BT    32                // tokens per block
#define BK    32                // k's per step
#define NSTEP (DIM / BK)        // 64 steps

typedef __attribute__((ext_vector_type(8))) short  short8;   // 8 bf16 in 4 VGPRs
typedef __attribute__((ext_vector_type(4))) float  f32x4;

#define MFMA16(a, b, c) __builtin_amdgcn_mfma_f32_16x16x32_bf16((a), (b), (c), 0, 0, 0)

// Static device storage: 3 bf16 planes (h,m,l) of wt[e][k] = 768 KB.
__device__ __align__(16) unsigned short g_wt[3 * WT_PLANE];

// ---------------------------------------------------------------------------
// Setup: transpose w [DIM][NEXP] -> wt[e][k], 3-way bf16 TRUNCATION split.
// h = top16(v); r1 = v-h exact; m = top16(r1); l = top16(r1-m).
// Coalesced 16B writes per thread. Also zeroes expert_activation.
// ---------------------------------------------------------------------------
__global__ void wsplit_kernel(const float* __restrict__ w,
                              float* __restrict__ out) {
    const int tid = threadIdx.x;           // 0..255
    const int e   = blockIdx.x;            // 0..63
    if (e == 0 && tid < NEXP) out[OFF_ACT + tid] = 0.0f;

    const int k0 = tid * 8;
    short8 hs, ms, ls;
    #pragma unroll
    for (int i = 0; i < 8; ++i) {
        const float v = w[(size_t)(k0 + i) * NEXP + e];
        const unsigned int bv = __builtin_bit_cast(unsigned int, v);
        const unsigned int hb = bv & 0xFFFF0000u;
        const float r1 = v - __builtin_bit_cast(float, hb);
        const unsigned int r1b = __builtin_bit_cast(unsigned int, r1);
        const unsigned int mb = r1b & 0xFFFF0000u;
        const float r2 = r1 - __builtin_bit_cast(float, mb);
        const unsigned int lb = __builtin_bit_cast(unsigned int, r2);
        hs[i] = (short)(hb >> 16);
        ms[i] = (short)(mb >> 16);
        ls[i] = (short)(lb >> 16);
    }
    *reinterpret_cast<short8*>(&g_wt[(size_t)e * DIM + k0])                = hs;
    *reinterpret_cast<short8*>(&g_wt[(size_t)e * DIM + k0 + WT_PLANE])     = ms;
    *reinterpret_cast<short8*>(&g_wt[(size_t)e * DIM + k0 + 2 * WT_PLANE]) = ls;
}

__device__ __forceinline__ void gload_lds16(const void* g, void* s) {
    __builtin_amdgcn_global_load_lds(
        (const __attribute__((address_space(1))) void*)g,
        (__attribute__((address_space(3))) void*)s, 16, 0, 0);
}

// fp32x8 -> bf16 truncation split (ah, am, al)
__device__ __forceinline__ void split8(const float4 a, const float4 b,
                                       short8& ah, short8& am, short8& al) {
    float v[8] = {a.x, a.y, a.z, a.w, b.x, b.y, b.z, b.w};
    #pragma unroll
    for (int i = 0; i < 8; ++i) {
        const unsigned int bv = __builtin_bit_cast(unsigned int, v[i]);
        const unsigned int hb = bv & 0xFFFF0000u;
        const float r1 = v[i] - __builtin_bit_cast(float, hb);
        const unsigned int r1b = __builtin_bit_cast(unsigned int, r1);
        const unsigned int mb = r1b & 0xFFFF0000u;
        const float r2 = r1 - __builtin_bit_cast(float, mb);
        const unsigned int lb = __builtin_bit_cast(unsigned int, r2);
        ah[i] = (short)(hb >> 16);
        am[i] = (short)(mb >> 16);
        al[i] = (short)(lb >> 16);
    }
}

// ---------------------------------------------------------------------------
// Router v4 — m97-shape block-cooperative staging.
// Block: 256 threads = 4 waves, tile = 32 tokens x 64 experts, grid 512
// (2 blocks/CU). K-loop: 64 steps of BK=32, double-buffered LDS for A
// (32x32 f32, rotation-swizzled chunks) and W (3 planes x 64e x 32k bf16,
// rotation-swizzled). All staging ops are 8-rows x 128B-contiguous
// global_load_lds dwordx4 (pre-swizzled source, linear LDS dest).
// Wave wv owns output sub-tile (rows (wv&1)*16..+16) x (experts
// (wv>>1)*32..+32): acc = 2 x f32x4 only. One __syncthreads per step
// (implicit vmcnt-drain before barrier makes the dbuf race-free).
// ---------------------------------------------------------------------------
__global__ __launch_bounds__(256, 2)
void router_kernel(const float* __restrict__ x,
                   const float* __restrict__ noise,
                   float* __restrict__ out) {
    __shared__ __align__(16) float          aS[2][BT * BK];        // 8 KB
    __shared__ __align__(16) unsigned short wS[2][3 * NEXP * BK];  // 24 KB
    __shared__ float scores[BT][68];                               // 8.7 KB
    __shared__ float nshs[BT][68];                                 // 8.7 KB
    __shared__ float g1s[BT], g2s[BT];
    __shared__ int   i1s[BT], i2s[BT];
    __shared__ float bins[NEXP];

    const int tid  = threadIdx.x;
    const int l    = tid & 63;
    const int wv   = __builtin_amdgcn_readfirstlane(tid >> 6);  // 0..3
    const int lrow = l & 15;
    const int lk   = l >> 4;          // 0..3
    const int brow = blockIdx.x * BT;

    if (tid < NEXP) bins[tid] = 0.0f;

    // Stage noise rows (32 x 64 f32 = 512 float4 over 256 thr x 2).
    #pragma unroll
    for (int i = 0; i < 2; ++i) {
        const int idx = tid + i * 256;
        const int r = idx >> 4, c = (idx & 15) * 4;
        *reinterpret_cast<float4*>(&nshs[r][c]) =
            *reinterpret_cast<const float4*>(noise + (size_t)(brow + r) * NEXP + c);
    }

    // ---- staging addresses (pre-swizzled global source, linear LDS dest) --
    // A op (1 per wave): rows 8*wv..+8, lane l -> row 8wv+(l>>3), 16B chunk
    // slot l&7; slot s of row r holds global chunk (s - r) & 7 (rotation).
    const int arow = wv * 8 + (l >> 3);
    const int agch = ((l & 7) - arow) & 7;
    const float* asrc = x + (size_t)(brow + arow) * DIM + agch * 4;
    float* adst = &aS[0][0] + wv * 256;   // +1024 per buf; HW adds l*16B

    // W ops (3 per wave): op = wv*3+t -> plane p = op>>2, e-group q = op&3.
    // lane l -> e = q*16 + (l>>2), slot l&3; slot s of row e holds global
    // chunk (s - e) & 3.
    const unsigned short* wsrc[3];
    unsigned short* wdst[3];
    #pragma unroll
    for (int t = 0; t < 3; ++t) {
        const int op = wv * 3 + t;
        const int p  = op >> 2, q = op & 3;
        const int e  = q * 16 + (l >> 2);
        const int gch = ((l & 3) - e) & 3;
        wsrc[t] = g_wt + (size_t)p * WT_PLANE + (size_t)e * DIM + gch * 8;
        wdst[t] = &wS[0][0] + p * 2048 + q * 512;  // +6144 per buf
    }

#define STAGE(bf, ss) do {                                            \
        gload_lds16(asrc + (ss) * BK,     adst    + (bf) * 1024);     \
        gload_lds16(wsrc[0] + (ss) * BK,  wdst[0] + (bf) * 6144);     \
        gload_lds16(wsrc[1] + (ss) * BK,  wdst[1] + (bf) * 6144);     \
        gload_lds16(wsrc[2] + (ss) * BK,  wdst[2] + (bf) * 6144);     \
    } while (0)

    // ---- per-wave fragment read addresses --------------------------------
    const int af = wv & 1;            // row-half of the tile
    const int n0 = (wv >> 1) * 2;     // first of two 16-expert fragments
    const int ar = af * 16 + lrow;    // A fragment row
    // A: two 16B chunks (k = lk*8..+4, +4..+8), rotation-stored.
    const int ac0 = ((2 * lk + ar) & 7) * 4;
    const int ac1 = ((2 * lk + 1 + ar) & 7) * 4;
    // W: per (n, plane): e = (n0+n)*16 + lrow, chunk lk rotation-stored.
    int woff[2];
    #pragma unroll
    for (int n = 0; n < 2; ++n) {
        const int e = (n0 + n) * 16 + lrow;
        woff[n] = e * 32 + ((lk + e) & 3) * 8;   // shorts, within a plane
    }

    f32x4 acc[2];
    acc[0] = (f32x4){0.f, 0.f, 0.f, 0.f};
    acc[1] = acc[0];

    STAGE(0, 0);
    __syncthreads();

    #pragma unroll 2
    for (int s = 0; s < NSTEP; ++s) {
        const int b = s & 1;
        const int sn = (s + 1 < NSTEP) ? (s + 1) : s;   // tail: restage, harmless
        STAGE(b ^ 1, sn);   // in flight across this step's compute

        // A fragment (8 fp32) from LDS, then bf16 split.
        const float* ab = &aS[b][ar * 32];
        const float4 xa0 = *reinterpret_cast<const float4*>(ab + ac0);
        const float4 xa1 = *reinterpret_cast<const float4*>(ab + ac1);
        short8 ah, am, al;
        split8(xa0, xa1, ah, am, al);

        // W fragments: 2 experts-groups x 3 planes.
        const unsigned short* wbuf = &wS[b][0];
        #pragma unroll
        for (int n = 0; n < 2; ++n) {
            const short8 Wh = *reinterpret_cast<const short8*>(wbuf +        woff[n]);
            const short8 Wm = *reinterpret_cast<const short8*>(wbuf + 2048 + woff[n]);
            const short8 Wl = *reinterpret_cast<const short8*>(wbuf + 4096 + woff[n]);
            // 6 split-products: h*h + h*m + m*h + h*l + m*m + l*h
            acc[n] = MFMA16(ah, Wh, acc[n]);
            acc[n] = MFMA16(ah, Wm, acc[n]);
            acc[n] = MFMA16(am, Wh, acc[n]);
            acc[n] = MFMA16(ah, Wl, acc[n]);
            acc[n] = MFMA16(am, Wm, acc[n]);
            acc[n] = MFMA16(al, Wh, acc[n]);
        }
        __syncthreads();   // implicit vmcnt drain: next buf landed, reads done
    }
#undef STAGE

    // C/D layout (m89-verified): col = lane&15, row = (lane>>4)*4 + reg.
    #pragma unroll
    for (int n = 0; n < 2; ++n)
        #pragma unroll
        for (int j = 0; j < 4; ++j)
            scores[af * 16 + lk * 4 + j][(n0 + n) * 16 + lrow] = acc[n][j];
    __syncthreads();

    // Epilogue: threads 0..31, one token row each. Add noise, top-2, gates.
    if (tid < BT) {
        const int r   = tid;
        const int row = brow + r;
        float m1 = -1e30f, m2 = -1e30f;
        int i1 = 0, i2 = 0;
        #pragma unroll
        for (int j = 0; j < NEXP; j += 4) {
            float4 s4       = *reinterpret_cast<const float4*>(&scores[r][j]);
            const float4 nv = *reinterpret_cast<const float4*>(&nshs[r][j]);
            s4.x += nv.x; s4.y += nv.y; s4.z += nv.z; s4.w += nv.w;
            if (s4.x > m1) { m2 = m1; i2 = i1; m1 = s4.x; i1 = j + 0; } else if (s4.x > m2) { m2 = s4.x; i2 = j + 0; }
            if (s4.y > m1) { m2 = m1; i2 = i1; m1 = s4.y; i1 = j + 1; } else if (s4.y > m2) { m2 = s4.y; i2 = j + 1; }
            if (s4.z > m1) { m2 = m1; i2 = i1; m1 = s4.z; i1 = j + 2; } else if (s4.z > m2) { m2 = s4.z; i2 = j + 2; }
            if (s4.w > m1) { m2 = m1; i2 = i1; m1 = s4.w; i1 = j + 3; } else if (s4.w > m2) { m2 = s4.w; i2 = j + 3; }
        }

        // Softmax Z cancels under top-2 renorm: g1 = 1/(1+exp(l2-l1)).
        const float t  = expf(m2 - m1);
        const float g1 = 1.0f / (1.0f + t);
        const float g2 = 1.0f - g1;

        out[OFF_IDX + row * 2 + 0]   = (float)i1;
        out[OFF_IDX + row * 2 + 1]   = (float)i2;
        out[OFF_GATES + row * 2 + 0] = g1;
        out[OFF_GATES + row * 2 + 1] = g2;

        g1s[r] = g1; g2s[r] = g2; i1s[r] = i1; i2s[r] = i2;
        atomicAdd(&bins[i1], 1.0f);
        atomicAdd(&bins[i2], 1.0f);
    }
    __syncthreads();

    // Combine tile write: 32 x 64 f32 = 512 float4 over 256 thr x 2.
    #pragma unroll
    for (int i = 0; i < 2; ++i) {
        const int idx = tid + i * 256;
        const int r = idx >> 4, c = (idx & 15) * 4;
        const int   a  = i1s[r], b = i2s[r];
        const float ga = g1s[r], gb = g2s[r];
        float4 v;
        v.x = (c + 0 == a) ? ga : (c + 0 == b) ? gb : 0.0f;
        v.y = (c + 1 == a) ? ga : (c + 1 == b) ? gb : 0.0f;
        v.z = (c + 2 == a) ? ga : (c + 2 == b) ? gb : 0.0f;
        v.w = (c + 3 == a) ? ga : (c + 3 == b) ? gb : 0.0f;
        *reinterpret_cast<float4*>(
            out + OFF_COMBINE + (size_t)(brow + r) * NEXP + c) = v;
    }

    if (tid < NEXP) {
        const float v = bins[tid];
        if (v != 0.0f) atomicAdd(out + OFF_ACT + tid, v);
    }
}

extern "C" void kernel_launch(void* const* d_in, const int* in_sizes, int n_in,
                              void* d_out, int out_size, void* d_ws, size_t ws_size,
                              hipStream_t stream) {
    const float* x     = (const float*)d_in[0];
    const float* wg    = (const float*)d_in[1];
    const float* noise = (const float*)d_in[2];
    float* out = (float*)d_out;

    wsplit_kernel<<<NEXP, 256, 0, stream>>>(wg, out);
    router_kernel<<<T_TOKENS / BT, 256, 0, stream>>>(x, noise, out);
}